// Round 7
// baseline (204.837 us; speedup 1.0000x reference)
//
#include <hip/hip_runtime.h>
#include <math.h>

// DeformAtten2D: B=4, H=W=C=128.
// R14: R13 post-mortem — attn's transpose/epilogue fixes were neutral: attn
// is latency/occupancy-bound across its phase chain, not store-bound. This
// round: k_attn3 row-split (R12-verified code): 2 blocks/head x 64 S-rows,
// LDS 71.7->53.2KB -> 3 blocks/CU (12 waves/CU) AND halved per-block
// GEMM/softmax chains; duplicated fixed work is only the vT build (~15%)
// + L2-hot k/Wo re-reads (the R12-fused3 mistake had ~50% duplication).
// k_fused3 (R11), k_off (R8), k_wprep unchanged.
#define IMG 16384   // 128*128

typedef short short4v __attribute__((ext_vector_type(4)));
typedef short short8  __attribute__((ext_vector_type(8)));
typedef float floatx4 __attribute__((ext_vector_type(4)));

__device__ __forceinline__ float4 ld4(const float* p) {
    return *reinterpret_cast<const float4*>(p);
}
__device__ __forceinline__ short f2bf(float f) {
    union { float f; unsigned u; } v; v.f = f;
    unsigned r = v.u + 0x7fffu + ((v.u >> 16) & 1u);   // RNE
    return (short)(r >> 16);
}
__device__ __forceinline__ float bf2f(short s) {
    union { unsigned u; float f; } v;
    v.u = ((unsigned)(unsigned short)s) << 16;
    return v.f;
}

// ---------------------------------------------------------------------------
// Kernel 1: blocks 0..49: o50=(t,tap) weight folding (W2, cst, b_eff) +
//           split-bf16 W2 (w2h/w2l). blocks 50..81: [Wq|Wk|Wv|Wo] -> bf16.
// ---------------------------------------------------------------------------
__launch_bounds__(256)
__global__ void k_wprep(const float* __restrict__ Wc1, const float* __restrict__ Wc2,
                        const float* __restrict__ bc1, const float* __restrict__ Wq,
                        const float* __restrict__ bq, const float* __restrict__ Wk,
                        const float* __restrict__ Wv, const float* __restrict__ Wo,
                        float* __restrict__ W2, float* __restrict__ cst,
                        float* __restrict__ b_eff, short* __restrict__ wbf,
                        short* __restrict__ w2h, short* __restrict__ w2l) {
    const int t = threadIdx.x;
    if (blockIdx.x >= 50) {                  // weight bf16 conversion
        if (blockIdx.x == 50) {              // zero-pad W2 split rows 50..63
            for (int i = t; i < 14 * 128; i += 256) {
                w2h[6400 + i] = 0;
                w2l[6400 + i] = 0;
            }
        }
        int i = (blockIdx.x - 50) * 256 + t;  // < 8192
        int base = i * 8;
        int sel = base >> 14, off = base & 16383;
        const float* s = (sel == 0) ? Wq : (sel == 1) ? Wk : (sel == 2) ? Wv : Wo;
        float4 a = ld4(s + off), b = ld4(s + off + 4);
        short8 o;
        o[0] = f2bf(a.x); o[1] = f2bf(a.y); o[2] = f2bf(a.z); o[3] = f2bf(a.w);
        o[4] = f2bf(b.x); o[5] = f2bf(b.y); o[6] = f2bf(b.z); o[7] = f2bf(b.w);
        *reinterpret_cast<short8*>(wbf + base) = o;
        return;
    }
    __shared__ float U[128];
    __shared__ float red[256];
    __shared__ float wc2[128];
    __shared__ float bql[128];
    const int tt = blockIdx.x;               // 0..49
    const int tch = tt / 25, tap = tt % 25;
    if (t < 128) { wc2[t] = Wc2[tch * 128 + t]; bql[t] = bq[t]; }
    __syncthreads();
    const int c = t & 127, half = t >> 7;
    float p = 0.f;
    for (int o = half * 64; o < half * 64 + 64; ++o)
        p += wc2[o] * Wc1[(o * 128 + c) * 25 + tap];
    red[half * 128 + c] = p;
    __syncthreads();
    if (t < 128) U[t] = red[t] + red[128 + t];
    __syncthreads();
    float p2 = 0.f;
    for (int cc = half * 64; cc < half * 64 + 64; ++cc)
        p2 += U[cc] * Wq[cc * 128 + c];
    red[half * 128 + c] = p2;
    __syncthreads();
    if (t < 128) {
        float vv = red[t] + red[128 + t];
        W2[tt * 128 + t] = vv;
        short hh = f2bf(vv);
        w2h[tt * 128 + t] = hh;
        w2l[tt * 128 + t] = f2bf(vv - bf2f(hh));
    }
    if (t < 128) red[t] = U[t] * bql[t];
    __syncthreads();
    if (t == 0) {
        float s = 0.f;
        for (int j = 0; j < 128; ++j) s += red[j];
        cst[tt] = s;
    }
    if (tap == 0) {
        __syncthreads();
        if (t < 128) red[t] = wc2[t] * bc1[t];
        __syncthreads();
        if (t == 0) {
            float s = 0.f;
            for (int j = 0; j < 128; ++j) s += red[j];
            b_eff[tch] = s;
        }
    }
}

// ---------------------------------------------------------------------------
// Kernel 2 (R8): P[b][o50][pix] = W2[o50]·x[pix] + cst[o50] via split-bf16
// MFMA (hh+hl+lh). 512 blocks x 128 px; wave w owns rows w*32..w*32+31.
// ---------------------------------------------------------------------------
__launch_bounds__(256, 2)
__global__ void k_off(const float* __restrict__ x, const short* __restrict__ w2h,
                      const short* __restrict__ w2l, const float* __restrict__ cst,
                      float* __restrict__ P, short* __restrict__ x_bf) {
    __shared__ __align__(16) float stage[64 * 132];   // 33792 B
    const int t = threadIdx.x;
    const int w = t >> 6, l = t & 63, l15 = l & 15, quad = l >> 4;
    const int p0 = blockIdx.x * 128;
    const int b = p0 >> 14, pix0 = p0 & (IMG - 1);

    floatx4 acc[2][4];
#pragma unroll
    for (int im = 0; im < 2; ++im)
#pragma unroll
        for (int in = 0; in < 4; ++in) acc[im][in] = (floatx4){0.f, 0.f, 0.f, 0.f};

    const float* xb = x + (size_t)p0 * 128;
    short* xbb = x_bf + (size_t)p0 * 128;

#pragma unroll
    for (int kc = 0; kc < 128; kc += 32) {
        short8 ah[2], al[2];
#pragma unroll
        for (int im = 0; im < 2; ++im) {
            int row = w * 32 + im * 16 + l15;
            const float* src = xb + row * 128 + kc + quad * 8;
            float4 f0 = ld4(src), f1 = ld4(src + 4);
            float fv[8] = {f0.x, f0.y, f0.z, f0.w, f1.x, f1.y, f1.z, f1.w};
            short8 h8, l8;
#pragma unroll
            for (int r = 0; r < 8; ++r) {
                short hh = f2bf(fv[r]);
                h8[r] = hh;
                l8[r] = f2bf(fv[r] - bf2f(hh));
            }
            ah[im] = h8; al[im] = l8;
            *reinterpret_cast<short8*>(xbb + row * 128 + kc + quad * 8) = h8;
        }
        short8 bh[4], bl[4];
#pragma unroll
        for (int in = 0; in < 4; ++in) {
            int o = in * 16 + l15;
            bh[in] = *reinterpret_cast<const short8*>(w2h + o * 128 + kc + quad * 8);
            bl[in] = *reinterpret_cast<const short8*>(w2l + o * 128 + kc + quad * 8);
        }
#pragma unroll
        for (int im = 0; im < 2; ++im)
#pragma unroll
            for (int in = 0; in < 4; ++in) {
                acc[im][in] = __builtin_amdgcn_mfma_f32_16x16x32_bf16(
                    ah[im], bh[in], acc[im][in], 0, 0, 0);
                acc[im][in] = __builtin_amdgcn_mfma_f32_16x16x32_bf16(
                    ah[im], bl[in], acc[im][in], 0, 0, 0);
                acc[im][in] = __builtin_amdgcn_mfma_f32_16x16x32_bf16(
                    al[im], bh[in], acc[im][in], 0, 0, 0);
            }
    }
    // stage P tile (o 0..63 x px 0..127) then coalesced write of o<50
#pragma unroll
    for (int im = 0; im < 2; ++im)
#pragma unroll
        for (int in = 0; in < 4; ++in) {
            int o = in * 16 + l15;
            int row0 = w * 32 + im * 16 + quad * 4;
            *reinterpret_cast<float4*>(&stage[o * 132 + row0]) =
                make_float4(acc[im][in][0], acc[im][in][1],
                            acc[im][in][2], acc[im][in][3]);
        }
    __syncthreads();
    for (int id = t; id < 50 * 32; id += 256) {
        int o = id >> 5, px4 = (id & 31) * 4;
        float c = cst[o];
        float4 v = *reinterpret_cast<float4*>(&stage[o * 132 + px4]);
        v.x += c; v.y += c; v.z += c; v.w += c;
        *reinterpret_cast<float4*>(P + ((size_t)(b * 50 + o)) * IMG + pix0 + px4) = v;
    }
}

// ---------------------------------------------------------------------------
// Kernel 3 (R11): FUSED per (b,h) row, 256 threads, 6 barriers.
//   A: P rows (branch-free clamped loads) -> zero-halo conv -> tanh*5 (LDS)
//   B: branch-free clamped bilinear gather, fully unrolled (8 items/thread,
//      ~32 loads in flight) -> xsT; q GEMM overlaps gather drain
//   C: stage q -> coalesced write; fused k&v GEMM; stage k->stg, v->xsT;
//      one combined write pass.
// LDS: stg/rowsP 34816 + xsT 34816 + offs 1024 = 70656 B (2 blocks/CU).
// ---------------------------------------------------------------------------
__launch_bounds__(256, 2)
__global__ void k_fused3(const float* __restrict__ P, const float* __restrict__ b_eff,
                         const short* __restrict__ x_bf, const short* __restrict__ wbf,
                         const float* __restrict__ bq, const float* __restrict__ bk,
                         const float* __restrict__ bv, const float* __restrict__ rel,
                         short* __restrict__ q_bf, short* __restrict__ k_bf,
                         short* __restrict__ v_bf) {
    __shared__ __align__(16) char smem[70656];
    float* rowsP  = (float*)smem;                // 27200 B (phase A only)
    short* stg    = (short*)smem;                // 34816 B stage (aliases rowsP)
    short* xsT    = (short*)(smem + 34816);      // 34816 B
    float* offs_l = (float*)(smem + 69632);      // 1024 B

    const int t = threadIdx.x;
    const int w = t >> 6, l = t & 63, l15 = l & 15, quad = l >> 4;
    const int mh = w >> 1, nh = w & 1;
    const int bh = blockIdx.x;
    const int b = bh >> 7, h = bh & 127;

    // ---- Phase A: P rows (5-row halo), branch-free clamped loads ----
    for (int id = t; id < 1600; id += 256) {
        int o = id >> 5, q4 = (id & 31) * 4;
        int di = (o % 25) / 5;
        int r = h + di - 2;
        int rc = min(max(r, 0), 127);
        float4 v = ld4(P + ((size_t)(b * 50 + o)) * IMG + rc * 128 + q4);
        float m = (r >= 0 && r < 128) ? 1.f : 0.f;
        v.x *= m; v.y *= m; v.z *= m; v.w *= m;
        *reinterpret_cast<float4*>(&rowsP[o * 136 + 4 + q4]) = v;
    }
    // zero the 4-col halos (cols 0..3 and 132..135) of each of 50 planes
    for (int id = t; id < 400; id += 256) {
        int o = id >> 3, c = id & 7;
        rowsP[o * 136 + (c < 4 ? c : 128 + c)] = 0.f;
    }
    __syncthreads();                             // B1
    {
        int wp = t & 127, tc = t >> 7;
        float acc = 0.f;
#pragma unroll
        for (int di = 0; di < 5; ++di)
#pragma unroll
            for (int dj = 0; dj < 5; ++dj)
                acc += rowsP[(tc * 25 + di * 5 + dj) * 136 + wp + dj + 2];
        offs_l[tc * 128 + wp] = tanhf(acc + b_eff[tc]) * 5.0f;
    }
    __syncthreads();                             // B2: offs ready, rowsP dead

    // ---- Phase B: branch-free bilinear gather -> xsT (no barrier yet) ----
    {
        const short* xbase = x_bf + (size_t)b * IMG * 128;
#pragma unroll
        for (int it = 0; it < 8; ++it) {
            int id = t + it * 256;
            int px = id >> 4, c8 = id & 15;
            float ox = offs_l[px];
            float oy = offs_l[128 + px];
            float xg = ((float)px + ox) * (128.0f / 127.0f) - 0.5f;
            float yg = ((float)h  + oy) * (128.0f / 127.0f) - 0.5f;
            float x0f = floorf(xg), y0f = floorf(yg);
            float fx = xg - x0f, fy = yg - y0f;
            int x0 = (int)x0f, y0 = (int)y0f;
            float s[8];
#pragma unroll
            for (int r = 0; r < 8; ++r) s[r] = 0.f;
#pragma unroll
            for (int tap = 0; tap < 4; ++tap) {
                int xi = x0 + (tap & 1), yi = y0 + (tap >> 1);
                float wgt = ((tap & 1) ? fx : 1.f - fx) * ((tap >> 1) ? fy : 1.f - fy);
                wgt = (xi >= 0 && xi < 128 && yi >= 0 && yi < 128) ? wgt : 0.f;
                int xc = min(max(xi, 0), 127), yc = min(max(yi, 0), 127);
                short8 v = *reinterpret_cast<const short8*>(
                    xbase + ((size_t)(yc * 128 + xc)) * 128 + c8 * 8);
#pragma unroll
                for (int r = 0; r < 8; ++r) s[r] = fmaf(wgt, bf2f(v[r]), s[r]);
            }
            short8 o;
#pragma unroll
            for (int r = 0; r < 8; ++r) o[r] = f2bf(s[r]);
            *reinterpret_cast<short8*>(&xsT[px * 136 + c8 * 8]) = o;
        }
    }

    // ---- q GEMM: A-frags direct from global x row (overlaps gather drain) ----
    {
        const short* xr = x_bf + ((size_t)(b * 128 + h)) * 128 * 128;
        floatx4 acc[4][4];
#pragma unroll
        for (int im = 0; im < 4; ++im)
#pragma unroll
            for (int in = 0; in < 4; ++in)
                acc[im][in] = (floatx4){0.f, 0.f, 0.f, 0.f};
#pragma unroll
        for (int kc = 0; kc < 128; kc += 32) {
            short8 af[4], bf_[4];
#pragma unroll
            for (int im = 0; im < 4; ++im)
                af[im] = *reinterpret_cast<const short8*>(
                    xr + (mh * 64 + im * 16 + l15) * 128 + kc + quad * 8);
#pragma unroll
            for (int in = 0; in < 4; ++in)
                bf_[in] = *reinterpret_cast<const short8*>(
                    wbf + (nh * 64 + in * 16 + l15) * 128 + kc + quad * 8);
#pragma unroll
            for (int im = 0; im < 4; ++im)
#pragma unroll
                for (int in = 0; in < 4; ++in)
                    acc[im][in] = __builtin_amdgcn_mfma_f32_16x16x32_bf16(
                        af[im], bf_[in], acc[im][in], 0, 0, 0);
        }
        __syncthreads();                         // B3: xsT complete, stg free
        // stage q: stg[col(plane)][row(px)]
#pragma unroll
        for (int in = 0; in < 4; ++in) {
            int o = nh * 64 + in * 16 + l15;
            float bb = bq[o];
#pragma unroll
            for (int im = 0; im < 4; ++im) {
                int row0 = mh * 64 + im * 16 + quad * 4;
                short4v s = {f2bf(acc[im][in][0] + bb), f2bf(acc[im][in][1] + bb),
                             f2bf(acc[im][in][2] + bb), f2bf(acc[im][in][3] + bb)};
                *reinterpret_cast<short4v*>(&stg[o * 136 + row0]) = s;
            }
        }
    }
    __syncthreads();                             // B4
    // coalesced q write
    for (int id = t; id < 2048; id += 256) {
        int o = id >> 4, seg = id & 15;
        *reinterpret_cast<short8*>(
            q_bf + ((size_t)(b * 128 + o)) * IMG + h * 128 + seg * 8)
            = *reinterpret_cast<const short8*>(&stg[o * 136 + seg * 8]);
    }

    // ---- fused k & v GEMMs (shared A-frags from xsT) ----
    {
        floatx4 ak[4][4], av[4][4];
#pragma unroll
        for (int im = 0; im < 4; ++im)
#pragma unroll
            for (int in = 0; in < 4; ++in) {
                ak[im][in] = (floatx4){0.f, 0.f, 0.f, 0.f};
                av[im][in] = (floatx4){0.f, 0.f, 0.f, 0.f};
            }
#pragma unroll
        for (int kc = 0; kc < 128; kc += 32) {
            short8 af[4], bk_[4], bv_[4];
#pragma unroll
            for (int im = 0; im < 4; ++im)
                af[im] = *reinterpret_cast<const short8*>(
                    &xsT[(mh * 64 + im * 16 + l15) * 136 + kc + quad * 8]);
#pragma unroll
            for (int in = 0; in < 4; ++in) {
                bk_[in] = *reinterpret_cast<const short8*>(
                    wbf + 16384 + (nh * 64 + in * 16 + l15) * 128 + kc + quad * 8);
                bv_[in] = *reinterpret_cast<const short8*>(
                    wbf + 32768 + (nh * 64 + in * 16 + l15) * 128 + kc + quad * 8);
            }
#pragma unroll
            for (int im = 0; im < 4; ++im)
#pragma unroll
                for (int in = 0; in < 4; ++in) {
                    ak[im][in] = __builtin_amdgcn_mfma_f32_16x16x32_bf16(
                        af[im], bk_[in], ak[im][in], 0, 0, 0);
                    av[im][in] = __builtin_amdgcn_mfma_f32_16x16x32_bf16(
                        af[im], bv_[in], av[im][in], 0, 0, 0);
                }
        }
        __syncthreads();                         // B5: q-write stg reads + xsT reads done
        // stage k -> stg, v -> xsT (simultaneously)
#pragma unroll
        for (int in = 0; in < 4; ++in) {
            int o = nh * 64 + in * 16 + l15;
            float bbk = bk[o];
            float bbv = bv[o] + rel[o * 128 + h];
#pragma unroll
            for (int im = 0; im < 4; ++im) {
                int row0 = mh * 64 + im * 16 + quad * 4;
                short4v sk = {f2bf(ak[im][in][0] + bbk), f2bf(ak[im][in][1] + bbk),
                              f2bf(ak[im][in][2] + bbk), f2bf(ak[im][in][3] + bbk)};
                short4v sv = {f2bf(av[im][in][0] + bbv), f2bf(av[im][in][1] + bbv),
                              f2bf(av[im][in][2] + bbv), f2bf(av[im][in][3] + bbv)};
                *reinterpret_cast<short4v*>(&stg[o * 136 + row0]) = sk;
                *reinterpret_cast<short4v*>(&xsT[o * 136 + row0]) = sv;
            }
        }
    }
    __syncthreads();                             // B6
    // combined coalesced k+v write
    for (int id = t; id < 4096; id += 256) {
        int sel = id >> 11;
        int o = (id >> 4) & 127, seg = id & 15;
        short* dst = sel ? v_bf : k_bf;
        const short* src = sel ? xsT : stg;
        *reinterpret_cast<short8*>(
            dst + ((size_t)(b * 128 + o)) * IMG + h * 128 + seg * 8)
            = *reinterpret_cast<const short8*>(&src[o * 136 + seg * 8]);
    }
}

// ---------------------------------------------------------------------------
// Kernel 4 (R14 = R12-verified split): MFMA attention, 2 blocks/head x 64
// S-rows. Grid 1024, 256 threads, LDS 53248 B -> 3 blocks/CU. Block =
// head*2 + half (pair adjacent -> shared L2 for k/v). Full k/v read per
// block; vT via b64-packed swizzled writes.
// ---------------------------------------------------------------------------
__launch_bounds__(256, 3)
__global__ void k_attn3(const short* __restrict__ q_bf, const short* __restrict__ k_bf,
                        const short* __restrict__ v_bf, const short* __restrict__ WoB,
                        const float* __restrict__ bo, float* __restrict__ outp) {
    __shared__ __align__(16) short vT[128 * 136];    // v^T, swizzled (34816 B)
    __shared__ __align__(16) short Pb[64 * 136];     // P bf16; then O (17408 B)
    __shared__ float redm[2 * 64];
    __shared__ float reds[2 * 64];

    const int t = threadIdx.x;
    const int w = t >> 6, l = t & 63, l15 = l & 15, quad = l >> 4;
    const int mh = w >> 1, nh = w & 1;
    const size_t hb = (size_t)(blockIdx.x >> 1) * IMG;
    const int i0 = (blockIdx.x & 1) << 6;            // row offset
    const short* qp = q_bf + hb;
    const short* kp = k_bf + hb;
    const short* vp = v_bf + hb;

    // ---- v -> vT transpose (b64 writes, swizzled): 512 items, 2/thread ----
    for (int id = t; id < 512; id += 256) {
        int j4 = id >> 4, seg = id & 15;             // j-block of 4, d-block of 8
        const short* src = vp + (j4 * 4) * 128 + seg * 8;
        short8 v0 = *reinterpret_cast<const short8*>(src);
        short8 v1 = *reinterpret_cast<const short8*>(src + 128);
        short8 v2 = *reinterpret_cast<const short8*>(src + 256);
        short8 v3 = *reinterpret_cast<const short8*>(src + 384);
        int phys = (((j4 >> 1) ^ seg) & 15) * 8 + (j4 & 1) * 4;
#pragma unroll
        for (int r = 0; r < 8; ++r) {
            short4v wv = {v0[r], v1[r], v2[r], v3[r]};
            *reinterpret_cast<short4v*>(&vT[(seg * 8 + r) * 136 + phys]) = wv;
        }
    }

    floatx4 acc[2][4];
#pragma unroll
    for (int im = 0; im < 2; ++im)
#pragma unroll
        for (int in = 0; in < 4; ++in)
            acc[im][in] = (floatx4){0.f, 0.f, 0.f, 0.f};

    // ---- Phase 1: S rows [i0,i0+64) = q·kT (direct-global frags) ----
#pragma unroll
    for (int kc = 0; kc < 128; kc += 32) {
        short8 af[2], bf_[4];
#pragma unroll
        for (int im = 0; im < 2; ++im)
            af[im] = *reinterpret_cast<const short8*>(
                qp + (i0 + mh * 32 + im * 16 + l15) * 128 + kc + quad * 8);
#pragma unroll
        for (int in = 0; in < 4; ++in)
            bf_[in] = *reinterpret_cast<const short8*>(
                kp + (nh * 64 + in * 16 + l15) * 128 + kc + quad * 8);
#pragma unroll
        for (int im = 0; im < 2; ++im)
#pragma unroll
            for (int in = 0; in < 4; ++in)
                acc[im][in] = __builtin_amdgcn_mfma_f32_16x16x32_bf16(
                    af[im], bf_[in], acc[im][in], 0, 0, 0);
    }

    const float scale = 0.08838834764831845f;
    float mloc[2][4];
#pragma unroll
    for (int im = 0; im < 2; ++im)
#pragma unroll
        for (int r = 0; r < 4; ++r) {
            float m = acc[im][0][r];
#pragma unroll
            for (int in = 1; in < 4; ++in) m = fmaxf(m, acc[im][in][r]);
            mloc[im][r] = m;
        }
#pragma unroll
    for (int mask = 1; mask < 16; mask <<= 1)
#pragma unroll
        for (int im = 0; im < 2; ++im)
#pragma unroll
            for (int r = 0; r < 4; ++r)
                mloc[im][r] = fmaxf(mloc[im][r], __shfl_xor(mloc[im][r], mask, 64));
    if (l15 == 0) {
#pragma unroll
        for (int im = 0; im < 2; ++im)
#pragma unroll
            for (int r = 0; r < 4; ++r)
                redm[nh * 64 + mh * 32 + im * 16 + quad * 4 + r] = mloc[im][r];
    }
    __syncthreads();
    float sloc[2][4];
#pragma unroll
    for (int im = 0; im < 2; ++im)
#pragma unroll
        for (int r = 0; r < 4; ++r) {
            int row = mh * 32 + im * 16 + quad * 4 + r;
            float m = fmaxf(redm[row], redm[64 + row]);
            float ss = 0.f;
#pragma unroll
            for (int in = 0; in < 4; ++in) {
                float e = __expf((acc[im][in][r] - m) * scale);
                acc[im][in][r] = e;
                ss += e;
            }
            sloc[im][r] = ss;
        }
#pragma unroll
    for (int mask = 1; mask < 16; mask <<= 1)
#pragma unroll
        for (int im = 0; im < 2; ++im)
#pragma unroll
            for (int r = 0; r < 4; ++r)
                sloc[im][r] += __shfl_xor(sloc[im][r], mask, 64);
    if (l15 == 0) {
#pragma unroll
        for (int im = 0; im < 2; ++im)
#pragma unroll
            for (int r = 0; r < 4; ++r)
                reds[nh * 64 + mh * 32 + im * 16 + quad * 4 + r] = sloc[im][r];
    }
    __syncthreads();
#pragma unroll
    for (int im = 0; im < 2; ++im)
#pragma unroll
        for (int r = 0; r < 4; ++r) {
            int row = mh * 32 + im * 16 + quad * 4 + r;
            float inv = 1.0f / (reds[row] + reds[64 + row]);
#pragma unroll
            for (int in = 0; in < 4; ++in) {
                int col = nh * 64 + in * 16 + l15;
                Pb[row * 136 + col] = f2bf(acc[im][in][r] * inv);
            }
        }
    __syncthreads();

    // ---- Phase 2: O = P·v  (A=Pb rows, B=vT swizzled, N=128) ----
#pragma unroll
    for (int im = 0; im < 2; ++im)
#pragma unroll
        for (int in = 0; in < 4; ++in)
            acc[im][in] = (floatx4){0.f, 0.f, 0.f, 0.f};
#pragma unroll
    for (int kc = 0; kc < 128; kc += 32) {
        short8 af[2], bf_[4];
#pragma unroll
        for (int im = 0; im < 2; ++im)
            af[im] = *reinterpret_cast<const short8*>(
                &Pb[(mh * 32 + im * 16 + l15) * 136 + kc + quad * 8]);
#pragma unroll
        for (int in = 0; in < 4; ++in) {
            int dRow = nh * 64 + in * 16 + l15;
            int cphys = (((kc >> 3) + quad) ^ (dRow >> 3)) & 15;
            bf_[in] = *reinterpret_cast<const short8*>(
                &vT[dRow * 136 + cphys * 8]);
        }
#pragma unroll
        for (int im = 0; im < 2; ++im)
#pragma unroll
            for (int in = 0; in < 4; ++in)
                acc[im][in] = __builtin_amdgcn_mfma_f32_16x16x32_bf16(
                    af[im], bf_[in], acc[im][in], 0, 0, 0);
    }
    __syncthreads();
#pragma unroll
    for (int im = 0; im < 2; ++im)
#pragma unroll
        for (int in = 0; in < 4; ++in) {
            int col = nh * 64 + in * 16 + l15;
#pragma unroll
            for (int r = 0; r < 4; ++r) {
                int row = mh * 32 + im * 16 + quad * 4 + r;
                Pb[row * 136 + col] = f2bf(acc[im][in][r]);
            }
        }
    __syncthreads();

    // ---- Phase 3: Y = O·WoT + bo ----
    float bb[4];
#pragma unroll
    for (int in = 0; in < 4; ++in) bb[in] = bo[nh * 64 + in * 16 + l15];
#pragma unroll
    for (int im = 0; im < 2; ++im)
#pragma unroll
        for (int in = 0; in < 4; ++in)
            acc[im][in] = (floatx4){0.f, 0.f, 0.f, 0.f};
#pragma unroll
    for (int kc = 0; kc < 128; kc += 32) {
        short8 af[2], bf_[4];
#pragma unroll
        for (int im = 0; im < 2; ++im)
            af[im] = *reinterpret_cast<const short8*>(
                &Pb[(mh * 32 + im * 16 + l15) * 136 + kc + quad * 8]);
#pragma unroll
        for (int in = 0; in < 4; ++in)
            bf_[in] = *reinterpret_cast<const short8*>(
                WoB + (nh * 64 + in * 16 + l15) * 128 + kc + quad * 8);
#pragma unroll
        for (int im = 0; im < 2; ++im)
#pragma unroll
            for (int in = 0; in < 4; ++in)
                acc[im][in] = __builtin_amdgcn_mfma_f32_16x16x32_bf16(
                    af[im], bf_[in], acc[im][in], 0, 0, 0);
    }
#pragma unroll
    for (int im = 0; im < 2; ++im)
#pragma unroll
        for (int in = 0; in < 4; ++in) {
            int col = nh * 64 + in * 16 + l15;
#pragma unroll
            for (int r = 0; r < 4; ++r) {
                int row = mh * 32 + im * 16 + quad * 4 + r;
                outp[hb + (size_t)(i0 + row) * 128 + col] = acc[im][in][r] + bb[in];
            }
        }
}

// ---------------------------------------------------------------------------
extern "C" void kernel_launch(void* const* d_in, const int* in_sizes, int n_in,
                              void* d_out, int out_size, void* d_ws, size_t ws_size,
                              hipStream_t stream) {
    const float* x   = (const float*)d_in[0];
    const float* Wq  = (const float*)d_in[2];
    const float* bq  = (const float*)d_in[3];
    const float* Wk  = (const float*)d_in[4];
    const float* bk  = (const float*)d_in[5];
    const float* Wv  = (const float*)d_in[6];
    const float* bv  = (const float*)d_in[7];
    const float* Wo  = (const float*)d_in[8];
    const float* bo  = (const float*)d_in[9];
    const float* Wc1 = (const float*)d_in[10];
    const float* bc1 = (const float*)d_in[11];
    const float* Wc2 = (const float*)d_in[12];
    const float* rel = (const float*)d_in[13];

    char* wsb = (char*)d_ws;
    short* q_bf  = (short*)(wsb);                       // 16 MB
    short* k_bf  = (short*)(wsb + 1ull * 16777216);
    short* v_bf  = (short*)(wsb + 2ull * 16777216);
    short* x_bf  = (short*)(wsb + 3ull * 16777216);
    float* P     = (float*)(wsb + 4ull * 16777216);     // 13.1 MB
    float* W2    = (float*)(wsb + 4ull * 16777216 + 13107200);
    float* cst   = W2 + 6400;
    float* b_eff = cst + 64;
    short* wbf   = (short*)(b_eff + 16);                // 4 x 16384 bf16
    short* w2h   = wbf + 65536;                         // 64x128 bf16 (hi)
    short* w2l   = w2h + 8192;                          // 64x128 bf16 (lo)
    float* outp  = (float*)d_out;

    hipLaunchKernelGGL(k_wprep,  dim3(82),   dim3(256), 0, stream, Wc1, Wc2, bc1, Wq, bq,
                       Wk, Wv, Wo, W2, cst, b_eff, wbf, w2h, w2l);
    hipLaunchKernelGGL(k_off,    dim3(512),  dim3(256), 0, stream, x, w2h, w2l, cst, P, x_bf);
    hipLaunchKernelGGL(k_fused3, dim3(512),  dim3(256), 0, stream, P, b_eff, x_bf, wbf,
                       bq, bk, bv, rel, q_bf, k_bf, v_bf);
    hipLaunchKernelGGL(k_attn3,  dim3(1024), dim3(256), 0, stream, q_bf, k_bf, v_bf,
                       wbf + 49152, bo, outp);
}

// Round 8
// 198.123 us; speedup vs baseline: 1.0339x; 1.0339x over previous
//
#include <hip/hip_runtime.h>
#include <math.h>

// DeformAtten2D: B=4, H=W=C=128.
// R15: R14 post-mortem — attn row-split regressed (duplicated vT build + k
// reads); reverted to unsplit attn. This round: ALGEBRAIC fold
// Y=(P·v)·Wo^T = P·(v·Wo^T). k_fused3 computes vw = v·Wo^T as a 4th MFMA
// GEMM (v already staged in xsT[plane][px]; contraction=px; D[o'][plane]
// orientation keeps staging+write coalesced) and stores vw into v_bf.
// k_attn3 loses Phase 3 entirely (-64 of 192 MFMA/thread, -Wo loads,
// -1 barrier pair, -O rewrite); Phase 2 acc + bo goes straight to the R13
// staged-coalesced fp32 write. HBM traffic unchanged.
#define IMG 16384   // 128*128

typedef short short4v __attribute__((ext_vector_type(4)));
typedef short short8  __attribute__((ext_vector_type(8)));
typedef float floatx4 __attribute__((ext_vector_type(4)));

__device__ __forceinline__ float4 ld4(const float* p) {
    return *reinterpret_cast<const float4*>(p);
}
__device__ __forceinline__ short f2bf(float f) {
    union { float f; unsigned u; } v; v.f = f;
    unsigned r = v.u + 0x7fffu + ((v.u >> 16) & 1u);   // RNE
    return (short)(r >> 16);
}
__device__ __forceinline__ float bf2f(short s) {
    union { unsigned u; float f; } v;
    v.u = ((unsigned)(unsigned short)s) << 16;
    return v.f;
}

// ---------------------------------------------------------------------------
// Kernel 1: blocks 0..49: o50=(t,tap) weight folding (W2, cst, b_eff) +
//           split-bf16 W2 (w2h/w2l). blocks 50..81: [Wq|Wk|Wv|Wo] -> bf16.
// ---------------------------------------------------------------------------
__launch_bounds__(256)
__global__ void k_wprep(const float* __restrict__ Wc1, const float* __restrict__ Wc2,
                        const float* __restrict__ bc1, const float* __restrict__ Wq,
                        const float* __restrict__ bq, const float* __restrict__ Wk,
                        const float* __restrict__ Wv, const float* __restrict__ Wo,
                        float* __restrict__ W2, float* __restrict__ cst,
                        float* __restrict__ b_eff, short* __restrict__ wbf,
                        short* __restrict__ w2h, short* __restrict__ w2l) {
    const int t = threadIdx.x;
    if (blockIdx.x >= 50) {                  // weight bf16 conversion
        if (blockIdx.x == 50) {              // zero-pad W2 split rows 50..63
            for (int i = t; i < 14 * 128; i += 256) {
                w2h[6400 + i] = 0;
                w2l[6400 + i] = 0;
            }
        }
        int i = (blockIdx.x - 50) * 256 + t;  // < 8192
        int base = i * 8;
        int sel = base >> 14, off = base & 16383;
        const float* s = (sel == 0) ? Wq : (sel == 1) ? Wk : (sel == 2) ? Wv : Wo;
        float4 a = ld4(s + off), b = ld4(s + off + 4);
        short8 o;
        o[0] = f2bf(a.x); o[1] = f2bf(a.y); o[2] = f2bf(a.z); o[3] = f2bf(a.w);
        o[4] = f2bf(b.x); o[5] = f2bf(b.y); o[6] = f2bf(b.z); o[7] = f2bf(b.w);
        *reinterpret_cast<short8*>(wbf + base) = o;
        return;
    }
    __shared__ float U[128];
    __shared__ float red[256];
    __shared__ float wc2[128];
    __shared__ float bql[128];
    const int tt = blockIdx.x;               // 0..49
    const int tch = tt / 25, tap = tt % 25;
    if (t < 128) { wc2[t] = Wc2[tch * 128 + t]; bql[t] = bq[t]; }
    __syncthreads();
    const int c = t & 127, half = t >> 7;
    float p = 0.f;
    for (int o = half * 64; o < half * 64 + 64; ++o)
        p += wc2[o] * Wc1[(o * 128 + c) * 25 + tap];
    red[half * 128 + c] = p;
    __syncthreads();
    if (t < 128) U[t] = red[t] + red[128 + t];
    __syncthreads();
    float p2 = 0.f;
    for (int cc = half * 64; cc < half * 64 + 64; ++cc)
        p2 += U[cc] * Wq[cc * 128 + c];
    red[half * 128 + c] = p2;
    __syncthreads();
    if (t < 128) {
        float vv = red[t] + red[128 + t];
        W2[tt * 128 + t] = vv;
        short hh = f2bf(vv);
        w2h[tt * 128 + t] = hh;
        w2l[tt * 128 + t] = f2bf(vv - bf2f(hh));
    }
    if (t < 128) red[t] = U[t] * bql[t];
    __syncthreads();
    if (t == 0) {
        float s = 0.f;
        for (int j = 0; j < 128; ++j) s += red[j];
        cst[tt] = s;
    }
    if (tap == 0) {
        __syncthreads();
        if (t < 128) red[t] = wc2[t] * bc1[t];
        __syncthreads();
        if (t == 0) {
            float s = 0.f;
            for (int j = 0; j < 128; ++j) s += red[j];
            b_eff[tch] = s;
        }
    }
}

// ---------------------------------------------------------------------------
// Kernel 2 (R8): P[b][o50][pix] = W2[o50]·x[pix] + cst[o50] via split-bf16
// MFMA (hh+hl+lh). 512 blocks x 128 px; wave w owns rows w*32..w*32+31.
// ---------------------------------------------------------------------------
__launch_bounds__(256, 2)
__global__ void k_off(const float* __restrict__ x, const short* __restrict__ w2h,
                      const short* __restrict__ w2l, const float* __restrict__ cst,
                      float* __restrict__ P, short* __restrict__ x_bf) {
    __shared__ __align__(16) float stage[64 * 132];   // 33792 B
    const int t = threadIdx.x;
    const int w = t >> 6, l = t & 63, l15 = l & 15, quad = l >> 4;
    const int p0 = blockIdx.x * 128;
    const int b = p0 >> 14, pix0 = p0 & (IMG - 1);

    floatx4 acc[2][4];
#pragma unroll
    for (int im = 0; im < 2; ++im)
#pragma unroll
        for (int in = 0; in < 4; ++in) acc[im][in] = (floatx4){0.f, 0.f, 0.f, 0.f};

    const float* xb = x + (size_t)p0 * 128;
    short* xbb = x_bf + (size_t)p0 * 128;

#pragma unroll
    for (int kc = 0; kc < 128; kc += 32) {
        short8 ah[2], al[2];
#pragma unroll
        for (int im = 0; im < 2; ++im) {
            int row = w * 32 + im * 16 + l15;
            const float* src = xb + row * 128 + kc + quad * 8;
            float4 f0 = ld4(src), f1 = ld4(src + 4);
            float fv[8] = {f0.x, f0.y, f0.z, f0.w, f1.x, f1.y, f1.z, f1.w};
            short8 h8, l8;
#pragma unroll
            for (int r = 0; r < 8; ++r) {
                short hh = f2bf(fv[r]);
                h8[r] = hh;
                l8[r] = f2bf(fv[r] - bf2f(hh));
            }
            ah[im] = h8; al[im] = l8;
            *reinterpret_cast<short8*>(xbb + row * 128 + kc + quad * 8) = h8;
        }
        short8 bh[4], bl[4];
#pragma unroll
        for (int in = 0; in < 4; ++in) {
            int o = in * 16 + l15;
            bh[in] = *reinterpret_cast<const short8*>(w2h + o * 128 + kc + quad * 8);
            bl[in] = *reinterpret_cast<const short8*>(w2l + o * 128 + kc + quad * 8);
        }
#pragma unroll
        for (int im = 0; im < 2; ++im)
#pragma unroll
            for (int in = 0; in < 4; ++in) {
                acc[im][in] = __builtin_amdgcn_mfma_f32_16x16x32_bf16(
                    ah[im], bh[in], acc[im][in], 0, 0, 0);
                acc[im][in] = __builtin_amdgcn_mfma_f32_16x16x32_bf16(
                    ah[im], bl[in], acc[im][in], 0, 0, 0);
                acc[im][in] = __builtin_amdgcn_mfma_f32_16x16x32_bf16(
                    al[im], bh[in], acc[im][in], 0, 0, 0);
            }
    }
    // stage P tile (o 0..63 x px 0..127) then coalesced write of o<50
#pragma unroll
    for (int im = 0; im < 2; ++im)
#pragma unroll
        for (int in = 0; in < 4; ++in) {
            int o = in * 16 + l15;
            int row0 = w * 32 + im * 16 + quad * 4;
            *reinterpret_cast<float4*>(&stage[o * 132 + row0]) =
                make_float4(acc[im][in][0], acc[im][in][1],
                            acc[im][in][2], acc[im][in][3]);
        }
    __syncthreads();
    for (int id = t; id < 50 * 32; id += 256) {
        int o = id >> 5, px4 = (id & 31) * 4;
        float c = cst[o];
        float4 v = *reinterpret_cast<float4*>(&stage[o * 132 + px4]);
        v.x += c; v.y += c; v.z += c; v.w += c;
        *reinterpret_cast<float4*>(P + ((size_t)(b * 50 + o)) * IMG + pix0 + px4) = v;
    }
}

// ---------------------------------------------------------------------------
// Kernel 3 (R15): FUSED per (b,h) row, 256 threads, 8 barriers.
//   A: P rows (branch-free clamped loads) -> zero-halo conv -> tanh*5 (LDS)
//   B: branch-free gather (8 items/thread) -> xsT; q GEMM overlaps drain
//   C: stage q -> write; fused k&v GEMM; stage k->stg, v->xsT; write k;
//      vw = v·Wo^T GEMM (A=Wo global rows, B=xsT v rows, D[o'][plane]);
//      stage vw -> stg; write vw into v_bf.
// LDS: stg/rowsP 34816 + xsT 34816 + offs 1024 = 70656 B (2 blocks/CU).
// ---------------------------------------------------------------------------
__launch_bounds__(256, 2)
__global__ void k_fused3(const float* __restrict__ P, const float* __restrict__ b_eff,
                         const short* __restrict__ x_bf, const short* __restrict__ wbf,
                         const float* __restrict__ bq, const float* __restrict__ bk,
                         const float* __restrict__ bv, const float* __restrict__ rel,
                         short* __restrict__ q_bf, short* __restrict__ k_bf,
                         short* __restrict__ v_bf) {
    __shared__ __align__(16) char smem[70656];
    float* rowsP  = (float*)smem;                // 27200 B (phase A only)
    short* stg    = (short*)smem;                // 34816 B stage (aliases rowsP)
    short* xsT    = (short*)(smem + 34816);      // 34816 B
    float* offs_l = (float*)(smem + 69632);      // 1024 B

    const int t = threadIdx.x;
    const int w = t >> 6, l = t & 63, l15 = l & 15, quad = l >> 4;
    const int mh = w >> 1, nh = w & 1;
    const int bh = blockIdx.x;
    const int b = bh >> 7, h = bh & 127;

    // ---- Phase A: P rows (5-row halo), branch-free clamped loads ----
    for (int id = t; id < 1600; id += 256) {
        int o = id >> 5, q4 = (id & 31) * 4;
        int di = (o % 25) / 5;
        int r = h + di - 2;
        int rc = min(max(r, 0), 127);
        float4 v = ld4(P + ((size_t)(b * 50 + o)) * IMG + rc * 128 + q4);
        float m = (r >= 0 && r < 128) ? 1.f : 0.f;
        v.x *= m; v.y *= m; v.z *= m; v.w *= m;
        *reinterpret_cast<float4*>(&rowsP[o * 136 + 4 + q4]) = v;
    }
    // zero the 4-col halos (cols 0..3 and 132..135) of each of 50 planes
    for (int id = t; id < 400; id += 256) {
        int o = id >> 3, c = id & 7;
        rowsP[o * 136 + (c < 4 ? c : 128 + c)] = 0.f;
    }
    __syncthreads();                             // B1
    {
        int wp = t & 127, tc = t >> 7;
        float acc = 0.f;
#pragma unroll
        for (int di = 0; di < 5; ++di)
#pragma unroll
            for (int dj = 0; dj < 5; ++dj)
                acc += rowsP[(tc * 25 + di * 5 + dj) * 136 + wp + dj + 2];
        offs_l[tc * 128 + wp] = tanhf(acc + b_eff[tc]) * 5.0f;
    }
    __syncthreads();                             // B2: offs ready, rowsP dead

    // ---- Phase B: branch-free bilinear gather -> xsT (no barrier yet) ----
    {
        const short* xbase = x_bf + (size_t)b * IMG * 128;
#pragma unroll
        for (int it = 0; it < 8; ++it) {
            int id = t + it * 256;
            int px = id >> 4, c8 = id & 15;
            float ox = offs_l[px];
            float oy = offs_l[128 + px];
            float xg = ((float)px + ox) * (128.0f / 127.0f) - 0.5f;
            float yg = ((float)h  + oy) * (128.0f / 127.0f) - 0.5f;
            float x0f = floorf(xg), y0f = floorf(yg);
            float fx = xg - x0f, fy = yg - y0f;
            int x0 = (int)x0f, y0 = (int)y0f;
            float s[8];
#pragma unroll
            for (int r = 0; r < 8; ++r) s[r] = 0.f;
#pragma unroll
            for (int tap = 0; tap < 4; ++tap) {
                int xi = x0 + (tap & 1), yi = y0 + (tap >> 1);
                float wgt = ((tap & 1) ? fx : 1.f - fx) * ((tap >> 1) ? fy : 1.f - fy);
                wgt = (xi >= 0 && xi < 128 && yi >= 0 && yi < 128) ? wgt : 0.f;
                int xc = min(max(xi, 0), 127), yc = min(max(yi, 0), 127);
                short8 v = *reinterpret_cast<const short8*>(
                    xbase + ((size_t)(yc * 128 + xc)) * 128 + c8 * 8);
#pragma unroll
                for (int r = 0; r < 8; ++r) s[r] = fmaf(wgt, bf2f(v[r]), s[r]);
            }
            short8 o;
#pragma unroll
            for (int r = 0; r < 8; ++r) o[r] = f2bf(s[r]);
            *reinterpret_cast<short8*>(&xsT[px * 136 + c8 * 8]) = o;
        }
    }

    // ---- q GEMM: A-frags direct from global x row (overlaps gather drain) ----
    {
        const short* xr = x_bf + ((size_t)(b * 128 + h)) * 128 * 128;
        floatx4 acc[4][4];
#pragma unroll
        for (int im = 0; im < 4; ++im)
#pragma unroll
            for (int in = 0; in < 4; ++in)
                acc[im][in] = (floatx4){0.f, 0.f, 0.f, 0.f};
#pragma unroll
        for (int kc = 0; kc < 128; kc += 32) {
            short8 af[4], bf_[4];
#pragma unroll
            for (int im = 0; im < 4; ++im)
                af[im] = *reinterpret_cast<const short8*>(
                    xr + (mh * 64 + im * 16 + l15) * 128 + kc + quad * 8);
#pragma unroll
            for (int in = 0; in < 4; ++in)
                bf_[in] = *reinterpret_cast<const short8*>(
                    wbf + (nh * 64 + in * 16 + l15) * 128 + kc + quad * 8);
#pragma unroll
            for (int im = 0; im < 4; ++im)
#pragma unroll
                for (int in = 0; in < 4; ++in)
                    acc[im][in] = __builtin_amdgcn_mfma_f32_16x16x32_bf16(
                        af[im], bf_[in], acc[im][in], 0, 0, 0);
        }
        __syncthreads();                         // B3: xsT complete, stg free
        // stage q: stg[col(plane)][row(px)]
#pragma unroll
        for (int in = 0; in < 4; ++in) {
            int o = nh * 64 + in * 16 + l15;
            float bb = bq[o];
#pragma unroll
            for (int im = 0; im < 4; ++im) {
                int row0 = mh * 64 + im * 16 + quad * 4;
                short4v s = {f2bf(acc[im][in][0] + bb), f2bf(acc[im][in][1] + bb),
                             f2bf(acc[im][in][2] + bb), f2bf(acc[im][in][3] + bb)};
                *reinterpret_cast<short4v*>(&stg[o * 136 + row0]) = s;
            }
        }
    }
    __syncthreads();                             // B4
    // coalesced q write
    for (int id = t; id < 2048; id += 256) {
        int o = id >> 4, seg = id & 15;
        *reinterpret_cast<short8*>(
            q_bf + ((size_t)(b * 128 + o)) * IMG + h * 128 + seg * 8)
            = *reinterpret_cast<const short8*>(&stg[o * 136 + seg * 8]);
    }

    // ---- fused k & v GEMMs (shared A-frags from xsT) ----
    {
        floatx4 ak[4][4], av[4][4];
#pragma unroll
        for (int im = 0; im < 4; ++im)
#pragma unroll
            for (int in = 0; in < 4; ++in) {
                ak[im][in] = (floatx4){0.f, 0.f, 0.f, 0.f};
                av[im][in] = (floatx4){0.f, 0.f, 0.f, 0.f};
            }
#pragma unroll
        for (int kc = 0; kc < 128; kc += 32) {
            short8 af[4], bk_[4], bv_[4];
#pragma unroll
            for (int im = 0; im < 4; ++im)
                af[im] = *reinterpret_cast<const short8*>(
                    &xsT[(mh * 64 + im * 16 + l15) * 136 + kc + quad * 8]);
#pragma unroll
            for (int in = 0; in < 4; ++in) {
                bk_[in] = *reinterpret_cast<const short8*>(
                    wbf + 16384 + (nh * 64 + in * 16 + l15) * 128 + kc + quad * 8);
                bv_[in] = *reinterpret_cast<const short8*>(
                    wbf + 32768 + (nh * 64 + in * 16 + l15) * 128 + kc + quad * 8);
            }
#pragma unroll
            for (int im = 0; im < 4; ++im)
#pragma unroll
                for (int in = 0; in < 4; ++in) {
                    ak[im][in] = __builtin_amdgcn_mfma_f32_16x16x32_bf16(
                        af[im], bk_[in], ak[im][in], 0, 0, 0);
                    av[im][in] = __builtin_amdgcn_mfma_f32_16x16x32_bf16(
                        af[im], bv_[in], av[im][in], 0, 0, 0);
                }
        }
        __syncthreads();                         // B5: q-write stg reads + xsT reads done
        // stage k -> stg, biased v -> xsT (simultaneously)
#pragma unroll
        for (int in = 0; in < 4; ++in) {
            int o = nh * 64 + in * 16 + l15;
            float bbk = bk[o];
            float bbv = bv[o] + rel[o * 128 + h];
#pragma unroll
            for (int im = 0; im < 4; ++im) {
                int row0 = mh * 64 + im * 16 + quad * 4;
                short4v sk = {f2bf(ak[im][in][0] + bbk), f2bf(ak[im][in][1] + bbk),
                              f2bf(ak[im][in][2] + bbk), f2bf(ak[im][in][3] + bbk)};
                short4v sv = {f2bf(av[im][in][0] + bbv), f2bf(av[im][in][1] + bbv),
                              f2bf(av[im][in][2] + bbv), f2bf(av[im][in][3] + bbv)};
                *reinterpret_cast<short4v*>(&stg[o * 136 + row0]) = sk;
                *reinterpret_cast<short4v*>(&xsT[o * 136 + row0]) = sv;
            }
        }
    }
    __syncthreads();                             // B6
    // coalesced k write
    for (int id = t; id < 2048; id += 256) {
        int o = id >> 4, seg = id & 15;
        *reinterpret_cast<short8*>(
            k_bf + ((size_t)(b * 128 + o)) * IMG + h * 128 + seg * 8)
            = *reinterpret_cast<const short8*>(&stg[o * 136 + seg * 8]);
    }

    // ---- vw = v·Wo^T GEMM: D[o'][plane] = Σ_px Wo[o'][px]·v[plane][px] ----
    {
        const short* WoB = wbf + 49152;
        floatx4 aw[4][4];
#pragma unroll
        for (int im = 0; im < 4; ++im)
#pragma unroll
            for (int in = 0; in < 4; ++in)
                aw[im][in] = (floatx4){0.f, 0.f, 0.f, 0.f};
#pragma unroll
        for (int kc = 0; kc < 128; kc += 32) {
            short8 af[4], bf_[4];
#pragma unroll
            for (int im = 0; im < 4; ++im)
                af[im] = *reinterpret_cast<const short8*>(
                    WoB + (mh * 64 + im * 16 + l15) * 128 + kc + quad * 8);
#pragma unroll
            for (int in = 0; in < 4; ++in)
                bf_[in] = *reinterpret_cast<const short8*>(
                    &xsT[(nh * 64 + in * 16 + l15) * 136 + kc + quad * 8]);
#pragma unroll
            for (int im = 0; im < 4; ++im)
#pragma unroll
                for (int in = 0; in < 4; ++in)
                    aw[im][in] = __builtin_amdgcn_mfma_f32_16x16x32_bf16(
                        af[im], bf_[in], aw[im][in], 0, 0, 0);
        }
        __syncthreads();                         // B7: k-write stg reads done
        // stage vw: stg[plane][o'] (contig-4 along o' = quad*4+r)
#pragma unroll
        for (int in = 0; in < 4; ++in) {
            int plane = nh * 64 + in * 16 + l15;
#pragma unroll
            for (int im = 0; im < 4; ++im) {
                int row0 = mh * 64 + im * 16 + quad * 4;   // o' base
                short4v s = {f2bf(aw[im][in][0]), f2bf(aw[im][in][1]),
                             f2bf(aw[im][in][2]), f2bf(aw[im][in][3])};
                *reinterpret_cast<short4v*>(&stg[plane * 136 + row0]) = s;
            }
        }
    }
    __syncthreads();                             // B8
    // coalesced vw write into v_bf
    for (int id = t; id < 2048; id += 256) {
        int o = id >> 4, seg = id & 15;
        *reinterpret_cast<short8*>(
            v_bf + ((size_t)(b * 128 + o)) * IMG + h * 128 + seg * 8)
            = *reinterpret_cast<const short8*>(&stg[o * 136 + seg * 8]);
    }
}

// ---------------------------------------------------------------------------
// Kernel 4 (R15): MFMA attention, 2 phases. Phase 1: S=q·kT + softmax.
// Phase 2: Y = P·vw + bo (Wo pre-folded into vw by k_fused3). b64-packed
// vw->vT transpose; Y staged fp32 in LDS -> coalesced float4 stores.
// LDS: Pb 34816 + vT 34816 + redm 1024 + reds 1024 = 71680 B (2 blocks/CU).
// ---------------------------------------------------------------------------
__launch_bounds__(256, 2)
__global__ void k_attn3(const short* __restrict__ q_bf, const short* __restrict__ k_bf,
                        const short* __restrict__ v_bf,
                        const float* __restrict__ bo, float* __restrict__ outp) {
    __shared__ __align__(16) char smem[71680];
    short* Pb   = (short*)smem;                  // 34816 B: P bf16
    short* vT   = (short*)(smem + 34816);        // 34816 B: vw^T swizzled
    float* Ystg = (float*)smem;                  // 128x132 fp32 = 67584 B (epilogue)
    float* redm = (float*)(smem + 69632);        // 512 B x2
    float* reds = (float*)(smem + 70656);        // 512 B x2

    const int t = threadIdx.x;
    const int w = t >> 6, l = t & 63, l15 = l & 15, quad = l >> 4;
    const int mh = w >> 1, nh = w & 1;
    const size_t hb = (size_t)blockIdx.x * IMG;
    const short* qp = q_bf + hb;
    const short* kp = k_bf + hb;
    const short* vp = v_bf + hb;

    // ---- vw -> vT transpose (b64 writes, swizzled): 512 items, 2/thread ----
    for (int id = t; id < 512; id += 256) {
        int j4 = id >> 4, seg = id & 15;             // j-block of 4, d-block of 8
        const short* src = vp + (j4 * 4) * 128 + seg * 8;
        short8 v0 = *reinterpret_cast<const short8*>(src);
        short8 v1 = *reinterpret_cast<const short8*>(src + 128);
        short8 v2 = *reinterpret_cast<const short8*>(src + 256);
        short8 v3 = *reinterpret_cast<const short8*>(src + 384);
        int phys = (((j4 >> 1) ^ seg) & 15) * 8 + (j4 & 1) * 4;
#pragma unroll
        for (int r = 0; r < 8; ++r) {
            short4v wv = {v0[r], v1[r], v2[r], v3[r]};
            *reinterpret_cast<short4v*>(&vT[(seg * 8 + r) * 136 + phys]) = wv;
        }
    }

    floatx4 acc[4][4];
#pragma unroll
    for (int im = 0; im < 4; ++im)
#pragma unroll
        for (int in = 0; in < 4; ++in)
            acc[im][in] = (floatx4){0.f, 0.f, 0.f, 0.f};

    // ---- Phase 1: S = q·kT (direct-global frags) ----
#pragma unroll
    for (int kc = 0; kc < 128; kc += 32) {
        short8 af[4], bf_[4];
#pragma unroll
        for (int im = 0; im < 4; ++im)
            af[im] = *reinterpret_cast<const short8*>(
                qp + (mh * 64 + im * 16 + l15) * 128 + kc + quad * 8);
#pragma unroll
        for (int in = 0; in < 4; ++in)
            bf_[in] = *reinterpret_cast<const short8*>(
                kp + (nh * 64 + in * 16 + l15) * 128 + kc + quad * 8);
#pragma unroll
        for (int im = 0; im < 4; ++im)
#pragma unroll
            for (int in = 0; in < 4; ++in)
                acc[im][in] = __builtin_amdgcn_mfma_f32_16x16x32_bf16(
                    af[im], bf_[in], acc[im][in], 0, 0, 0);
    }

    const float scale = 0.08838834764831845f;
    float mloc[4][4];
#pragma unroll
    for (int im = 0; im < 4; ++im)
#pragma unroll
        for (int r = 0; r < 4; ++r) {
            float m = acc[im][0][r];
#pragma unroll
            for (int in = 1; in < 4; ++in) m = fmaxf(m, acc[im][in][r]);
            mloc[im][r] = m;
        }
#pragma unroll
    for (int mask = 1; mask < 16; mask <<= 1)
#pragma unroll
        for (int im = 0; im < 4; ++im)
#pragma unroll
            for (int r = 0; r < 4; ++r)
                mloc[im][r] = fmaxf(mloc[im][r], __shfl_xor(mloc[im][r], mask, 64));
    if (l15 == 0) {
#pragma unroll
        for (int im = 0; im < 4; ++im)
#pragma unroll
            for (int r = 0; r < 4; ++r)
                redm[nh * 128 + mh * 64 + im * 16 + quad * 4 + r] = mloc[im][r];
    }
    __syncthreads();
    float sloc[4][4];
#pragma unroll
    for (int im = 0; im < 4; ++im)
#pragma unroll
        for (int r = 0; r < 4; ++r) {
            int row = mh * 64 + im * 16 + quad * 4 + r;
            float m = fmaxf(redm[row], redm[128 + row]);
            float ss = 0.f;
#pragma unroll
            for (int in = 0; in < 4; ++in) {
                float e = __expf((acc[im][in][r] - m) * scale);
                acc[im][in][r] = e;
                ss += e;
            }
            sloc[im][r] = ss;
        }
#pragma unroll
    for (int mask = 1; mask < 16; mask <<= 1)
#pragma unroll
        for (int im = 0; im < 4; ++im)
#pragma unroll
            for (int r = 0; r < 4; ++r)
                sloc[im][r] += __shfl_xor(sloc[im][r], mask, 64);
    if (l15 == 0) {
#pragma unroll
        for (int im = 0; im < 4; ++im)
#pragma unroll
            for (int r = 0; r < 4; ++r)
                reds[nh * 128 + mh * 64 + im * 16 + quad * 4 + r] = sloc[im][r];
    }
    __syncthreads();
#pragma unroll
    for (int im = 0; im < 4; ++im)
#pragma unroll
        for (int r = 0; r < 4; ++r) {
            int row = mh * 64 + im * 16 + quad * 4 + r;
            float inv = 1.0f / (reds[row] + reds[128 + row]);
#pragma unroll
            for (int in = 0; in < 4; ++in) {
                int col = nh * 64 + in * 16 + l15;
                Pb[row * 136 + col] = f2bf(acc[im][in][r] * inv);
            }
        }
    __syncthreads();

    // ---- Phase 2: Y = P·vw (A=Pb, B=vT swizzled) + bo ----
    float bb[4];
#pragma unroll
    for (int in = 0; in < 4; ++in) bb[in] = bo[nh * 64 + in * 16 + l15];
#pragma unroll
    for (int im = 0; im < 4; ++im)
#pragma unroll
        for (int in = 0; in < 4; ++in)
            acc[im][in] = (floatx4){0.f, 0.f, 0.f, 0.f};
#pragma unroll
    for (int kc = 0; kc < 128; kc += 32) {
        short8 af[4], bf_[4];
#pragma unroll
        for (int im = 0; im < 4; ++im)
            af[im] = *reinterpret_cast<const short8*>(
                &Pb[(mh * 64 + im * 16 + l15) * 136 + kc + quad * 8]);
#pragma unroll
        for (int in = 0; in < 4; ++in) {
            int dRow = nh * 64 + in * 16 + l15;
            int cphys = (((kc >> 3) + quad) ^ (dRow >> 3)) & 15;
            bf_[in] = *reinterpret_cast<const short8*>(
                &vT[dRow * 136 + cphys * 8]);
        }
#pragma unroll
        for (int im = 0; im < 4; ++im)
#pragma unroll
            for (int in = 0; in < 4; ++in)
                acc[im][in] = __builtin_amdgcn_mfma_f32_16x16x32_bf16(
                    af[im], bf_[in], acc[im][in], 0, 0, 0);
    }
    __syncthreads();                             // Pb/vT reads done; Ystg aliases
#pragma unroll
    for (int im = 0; im < 4; ++im)
#pragma unroll
        for (int in = 0; in < 4; ++in) {
            int col = nh * 64 + in * 16 + l15;
#pragma unroll
            for (int r = 0; r < 4; ++r) {
                int row = mh * 64 + im * 16 + quad * 4 + r;
                Ystg[row * 132 + col] = acc[im][in][r] + bb[in];
            }
        }
    __syncthreads();
    // coalesced Y write: 4096 float4, 16/thread
    for (int id = t; id < 4096; id += 256) {
        int row = id >> 5, c4 = (id & 31) * 4;
        *reinterpret_cast<float4*>(outp + hb + (size_t)row * 128 + c4) =
            *reinterpret_cast<const float4*>(&Ystg[row * 132 + c4]);
    }
}

// ---------------------------------------------------------------------------
extern "C" void kernel_launch(void* const* d_in, const int* in_sizes, int n_in,
                              void* d_out, int out_size, void* d_ws, size_t ws_size,
                              hipStream_t stream) {
    const float* x   = (const float*)d_in[0];
    const float* Wq  = (const float*)d_in[2];
    const float* bq  = (const float*)d_in[3];
    const float* Wk  = (const float*)d_in[4];
    const float* bk  = (const float*)d_in[5];
    const float* Wv  = (const float*)d_in[6];
    const float* bv  = (const float*)d_in[7];
    const float* Wo  = (const float*)d_in[8];
    const float* bo  = (const float*)d_in[9];
    const float* Wc1 = (const float*)d_in[10];
    const float* bc1 = (const float*)d_in[11];
    const float* Wc2 = (const float*)d_in[12];
    const float* rel = (const float*)d_in[13];

    char* wsb = (char*)d_ws;
    short* q_bf  = (short*)(wsb);                       // 16 MB
    short* k_bf  = (short*)(wsb + 1ull * 16777216);
    short* v_bf  = (short*)(wsb + 2ull * 16777216);
    short* x_bf  = (short*)(wsb + 3ull * 16777216);
    float* P     = (float*)(wsb + 4ull * 16777216);     // 13.1 MB
    float* W2    = (float*)(wsb + 4ull * 16777216 + 13107200);
    float* cst   = W2 + 6400;
    float* b_eff = cst + 64;
    short* wbf   = (short*)(b_eff + 16);                // 4 x 16384 bf16
    short* w2h   = wbf + 65536;                         // 64x128 bf16 (hi)
    short* w2l   = w2h + 8192;                          // 64x128 bf16 (lo)
    float* outp  = (float*)d_out;

    hipLaunchKernelGGL(k_wprep,  dim3(82),   dim3(256), 0, stream, Wc1, Wc2, bc1, Wq, bq,
                       Wk, Wv, Wo, W2, cst, b_eff, wbf, w2h, w2l);
    hipLaunchKernelGGL(k_off,    dim3(512),  dim3(256), 0, stream, x, w2h, w2l, cst, P, x_bf);
    hipLaunchKernelGGL(k_fused3, dim3(512),  dim3(256), 0, stream, P, b_eff, x_bf, wbf,
                       bq, bk, bv, rel, q_bf, k_bf, v_bf);
    hipLaunchKernelGGL(k_attn3,  dim3(512),  dim3(256), 0, stream, q_bf, k_bf, v_bf,
                       bo, outp);
}

// Round 9
// 196.464 us; speedup vs baseline: 1.0426x; 1.0084x over previous
//
#include <hip/hip_runtime.h>
#include <math.h>

// DeformAtten2D: B=4, H=W=C=128.
// R16: R15 calibration — a serial GEMM+stage+write phase costs ~7-10us in
// these latency-bound kernels. The q GEMM is such a phase in k_fused3 but
// is nearly FREE in k_off: k_off's blocks are exactly one (b,h) row and
// already hold the bf16 x A-frags (ah) in registers. Move q there (+8
// L2-hot B-frags +16 MFMA per K-chunk in the existing barrier-free loop,
// +1 staged write pass; bit-identical q output). k_fused3 drops the whole
// q phase (8->7 barriers). vw fold (R15) kept; attn unchanged.
#define IMG 16384   // 128*128

typedef short short4v __attribute__((ext_vector_type(4)));
typedef short short8  __attribute__((ext_vector_type(8)));
typedef float floatx4 __attribute__((ext_vector_type(4)));

__device__ __forceinline__ float4 ld4(const float* p) {
    return *reinterpret_cast<const float4*>(p);
}
__device__ __forceinline__ short f2bf(float f) {
    union { float f; unsigned u; } v; v.f = f;
    unsigned r = v.u + 0x7fffu + ((v.u >> 16) & 1u);   // RNE
    return (short)(r >> 16);
}
__device__ __forceinline__ float bf2f(short s) {
    union { unsigned u; float f; } v;
    v.u = ((unsigned)(unsigned short)s) << 16;
    return v.f;
}

// ---------------------------------------------------------------------------
// Kernel 1: blocks 0..49: o50=(t,tap) weight folding (W2, cst, b_eff) +
//           split-bf16 W2 (w2h/w2l). blocks 50..81: [Wq|Wk|Wv|Wo] -> bf16.
// ---------------------------------------------------------------------------
__launch_bounds__(256)
__global__ void k_wprep(const float* __restrict__ Wc1, const float* __restrict__ Wc2,
                        const float* __restrict__ bc1, const float* __restrict__ Wq,
                        const float* __restrict__ bq, const float* __restrict__ Wk,
                        const float* __restrict__ Wv, const float* __restrict__ Wo,
                        float* __restrict__ W2, float* __restrict__ cst,
                        float* __restrict__ b_eff, short* __restrict__ wbf,
                        short* __restrict__ w2h, short* __restrict__ w2l) {
    const int t = threadIdx.x;
    if (blockIdx.x >= 50) {                  // weight bf16 conversion
        if (blockIdx.x == 50) {              // zero-pad W2 split rows 50..63
            for (int i = t; i < 14 * 128; i += 256) {
                w2h[6400 + i] = 0;
                w2l[6400 + i] = 0;
            }
        }
        int i = (blockIdx.x - 50) * 256 + t;  // < 8192
        int base = i * 8;
        int sel = base >> 14, off = base & 16383;
        const float* s = (sel == 0) ? Wq : (sel == 1) ? Wk : (sel == 2) ? Wv : Wo;
        float4 a = ld4(s + off), b = ld4(s + off + 4);
        short8 o;
        o[0] = f2bf(a.x); o[1] = f2bf(a.y); o[2] = f2bf(a.z); o[3] = f2bf(a.w);
        o[4] = f2bf(b.x); o[5] = f2bf(b.y); o[6] = f2bf(b.z); o[7] = f2bf(b.w);
        *reinterpret_cast<short8*>(wbf + base) = o;
        return;
    }
    __shared__ float U[128];
    __shared__ float red[256];
    __shared__ float wc2[128];
    __shared__ float bql[128];
    const int tt = blockIdx.x;               // 0..49
    const int tch = tt / 25, tap = tt % 25;
    if (t < 128) { wc2[t] = Wc2[tch * 128 + t]; bql[t] = bq[t]; }
    __syncthreads();
    const int c = t & 127, half = t >> 7;
    float p = 0.f;
    for (int o = half * 64; o < half * 64 + 64; ++o)
        p += wc2[o] * Wc1[(o * 128 + c) * 25 + tap];
    red[half * 128 + c] = p;
    __syncthreads();
    if (t < 128) U[t] = red[t] + red[128 + t];
    __syncthreads();
    float p2 = 0.f;
    for (int cc = half * 64; cc < half * 64 + 64; ++cc)
        p2 += U[cc] * Wq[cc * 128 + c];
    red[half * 128 + c] = p2;
    __syncthreads();
    if (t < 128) {
        float vv = red[t] + red[128 + t];
        W2[tt * 128 + t] = vv;
        short hh = f2bf(vv);
        w2h[tt * 128 + t] = hh;
        w2l[tt * 128 + t] = f2bf(vv - bf2f(hh));
    }
    if (t < 128) red[t] = U[t] * bql[t];
    __syncthreads();
    if (t == 0) {
        float s = 0.f;
        for (int j = 0; j < 128; ++j) s += red[j];
        cst[tt] = s;
    }
    if (tap == 0) {
        __syncthreads();
        if (t < 128) red[t] = wc2[t] * bc1[t];
        __syncthreads();
        if (t == 0) {
            float s = 0.f;
            for (int j = 0; j < 128; ++j) s += red[j];
            b_eff[tch] = s;
        }
    }
}

// ---------------------------------------------------------------------------
// Kernel 2 (R16): P[b][o50][pix] = W2·x + cst (split-bf16 hh+hl+lh) AND
// q[b][o][pix] = x·Wq^T + bq (bf16, bit-identical to fused3's old q GEMM —
// ah frags ARE x_bf). 512 blocks; block = one (b,h) row of 128 px.
// Epilogue: stage P fp32 -> write; stage q bf16 (same smem) -> write.
// ---------------------------------------------------------------------------
__launch_bounds__(256, 2)
__global__ void k_off(const float* __restrict__ x, const short* __restrict__ w2h,
                      const short* __restrict__ w2l, const float* __restrict__ cst,
                      const float* __restrict__ bq, const short* __restrict__ wbf,
                      float* __restrict__ P, short* __restrict__ x_bf,
                      short* __restrict__ q_bf) {
    __shared__ __align__(16) char smem[34816];
    float* stageF = (float*)smem;                 // 64x132 fp32 (P) = 33792 B
    short* stageS = (short*)smem;                 // 128x136 bf16 (q) = 34816 B
    const int t = threadIdx.x;
    const int w = t >> 6, l = t & 63, l15 = l & 15, quad = l >> 4;
    const int p0 = blockIdx.x * 128;
    const int b = p0 >> 14, pix0 = p0 & (IMG - 1);
    const int h = pix0 >> 7;                      // image row of this block

    floatx4 accP[2][4];
    floatx4 accQ[2][8];
#pragma unroll
    for (int im = 0; im < 2; ++im) {
#pragma unroll
        for (int in = 0; in < 4; ++in) accP[im][in] = (floatx4){0.f, 0.f, 0.f, 0.f};
#pragma unroll
        for (int in = 0; in < 8; ++in) accQ[im][in] = (floatx4){0.f, 0.f, 0.f, 0.f};
    }

    const float* xb = x + (size_t)p0 * 128;
    short* xbb = x_bf + (size_t)p0 * 128;

#pragma unroll
    for (int kc = 0; kc < 128; kc += 32) {
        short8 ah[2], al[2];
#pragma unroll
        for (int im = 0; im < 2; ++im) {
            int row = w * 32 + im * 16 + l15;
            const float* src = xb + row * 128 + kc + quad * 8;
            float4 f0 = ld4(src), f1 = ld4(src + 4);
            float fv[8] = {f0.x, f0.y, f0.z, f0.w, f1.x, f1.y, f1.z, f1.w};
            short8 h8, l8;
#pragma unroll
            for (int r = 0; r < 8; ++r) {
                short hh = f2bf(fv[r]);
                h8[r] = hh;
                l8[r] = f2bf(fv[r] - bf2f(hh));
            }
            ah[im] = h8; al[im] = l8;
            *reinterpret_cast<short8*>(xbb + row * 128 + kc + quad * 8) = h8;
        }
        short8 bh[4], bl[4], bqf[8];
#pragma unroll
        for (int in = 0; in < 4; ++in) {
            int o = in * 16 + l15;
            bh[in] = *reinterpret_cast<const short8*>(w2h + o * 128 + kc + quad * 8);
            bl[in] = *reinterpret_cast<const short8*>(w2l + o * 128 + kc + quad * 8);
        }
#pragma unroll
        for (int in = 0; in < 8; ++in)
            bqf[in] = *reinterpret_cast<const short8*>(
                wbf + (in * 16 + l15) * 128 + kc + quad * 8);
#pragma unroll
        for (int im = 0; im < 2; ++im) {
#pragma unroll
            for (int in = 0; in < 4; ++in) {
                accP[im][in] = __builtin_amdgcn_mfma_f32_16x16x32_bf16(
                    ah[im], bh[in], accP[im][in], 0, 0, 0);
                accP[im][in] = __builtin_amdgcn_mfma_f32_16x16x32_bf16(
                    ah[im], bl[in], accP[im][in], 0, 0, 0);
                accP[im][in] = __builtin_amdgcn_mfma_f32_16x16x32_bf16(
                    al[im], bh[in], accP[im][in], 0, 0, 0);
            }
#pragma unroll
            for (int in = 0; in < 8; ++in)
                accQ[im][in] = __builtin_amdgcn_mfma_f32_16x16x32_bf16(
                    ah[im], bqf[in], accQ[im][in], 0, 0, 0);
        }
    }
    // ---- stage P tile (o 0..63 x px 0..127) then coalesced write of o<50 ----
#pragma unroll
    for (int im = 0; im < 2; ++im)
#pragma unroll
        for (int in = 0; in < 4; ++in) {
            int o = in * 16 + l15;
            int row0 = w * 32 + im * 16 + quad * 4;
            *reinterpret_cast<float4*>(&stageF[o * 132 + row0]) =
                make_float4(accP[im][in][0], accP[im][in][1],
                            accP[im][in][2], accP[im][in][3]);
        }
    __syncthreads();
    for (int id = t; id < 50 * 32; id += 256) {
        int o = id >> 5, px4 = (id & 31) * 4;
        float c = cst[o];
        float4 v = *reinterpret_cast<float4*>(&stageF[o * 132 + px4]);
        v.x += c; v.y += c; v.z += c; v.w += c;
        *reinterpret_cast<float4*>(P + ((size_t)(b * 50 + o)) * IMG + pix0 + px4) = v;
    }
    __syncthreads();                              // stageF reads done
    // ---- stage q bf16 (o 0..127 x px 0..127) ----
#pragma unroll
    for (int in = 0; in < 8; ++in) {
        int o = in * 16 + l15;
        float bb = bq[o];
#pragma unroll
        for (int im = 0; im < 2; ++im) {
            int row0 = w * 32 + im * 16 + quad * 4;
            short4v s = {f2bf(accQ[im][in][0] + bb), f2bf(accQ[im][in][1] + bb),
                         f2bf(accQ[im][in][2] + bb), f2bf(accQ[im][in][3] + bb)};
            *reinterpret_cast<short4v*>(&stageS[o * 136 + row0]) = s;
        }
    }
    __syncthreads();
    // coalesced q write
    for (int id = t; id < 2048; id += 256) {
        int o = id >> 4, seg = id & 15;
        *reinterpret_cast<short8*>(
            q_bf + ((size_t)(b * 128 + o)) * IMG + h * 128 + seg * 8)
            = *reinterpret_cast<const short8*>(&stageS[o * 136 + seg * 8]);
    }
}

// ---------------------------------------------------------------------------
// Kernel 3 (R16): FUSED per (b,h) row, 256 threads, 7 barriers (q phase
// moved to k_off).
//   A: P rows (branch-free clamped loads) -> zero-halo conv -> tanh*5 (LDS)
//   B: branch-free gather (8 items/thread) -> xsT
//   C: fused k&v GEMM; stage k->stg, v->xsT; write k;
//      vw = v·Wo^T GEMM (D[o'][plane]); stage vw -> stg; write vw -> v_bf.
// LDS: stg/rowsP 34816 + xsT 34816 + offs 1024 = 70656 B (2 blocks/CU).
// ---------------------------------------------------------------------------
__launch_bounds__(256, 2)
__global__ void k_fused3(const float* __restrict__ P, const float* __restrict__ b_eff,
                         const short* __restrict__ x_bf, const short* __restrict__ wbf,
                         const float* __restrict__ bk, const float* __restrict__ bv,
                         const float* __restrict__ rel,
                         short* __restrict__ k_bf, short* __restrict__ v_bf) {
    __shared__ __align__(16) char smem[70656];
    float* rowsP  = (float*)smem;                // 27200 B (phase A only)
    short* stg    = (short*)smem;                // 34816 B stage (aliases rowsP)
    short* xsT    = (short*)(smem + 34816);      // 34816 B
    float* offs_l = (float*)(smem + 69632);      // 1024 B

    const int t = threadIdx.x;
    const int w = t >> 6, l = t & 63, l15 = l & 15, quad = l >> 4;
    const int mh = w >> 1, nh = w & 1;
    const int bh = blockIdx.x;
    const int b = bh >> 7, h = bh & 127;

    // ---- Phase A: P rows (5-row halo), branch-free clamped loads ----
    for (int id = t; id < 1600; id += 256) {
        int o = id >> 5, q4 = (id & 31) * 4;
        int di = (o % 25) / 5;
        int r = h + di - 2;
        int rc = min(max(r, 0), 127);
        float4 v = ld4(P + ((size_t)(b * 50 + o)) * IMG + rc * 128 + q4);
        float m = (r >= 0 && r < 128) ? 1.f : 0.f;
        v.x *= m; v.y *= m; v.z *= m; v.w *= m;
        *reinterpret_cast<float4*>(&rowsP[o * 136 + 4 + q4]) = v;
    }
    // zero the 4-col halos (cols 0..3 and 132..135) of each of 50 planes
    for (int id = t; id < 400; id += 256) {
        int o = id >> 3, c = id & 7;
        rowsP[o * 136 + (c < 4 ? c : 128 + c)] = 0.f;
    }
    __syncthreads();                             // B1
    {
        int wp = t & 127, tc = t >> 7;
        float acc = 0.f;
#pragma unroll
        for (int di = 0; di < 5; ++di)
#pragma unroll
            for (int dj = 0; dj < 5; ++dj)
                acc += rowsP[(tc * 25 + di * 5 + dj) * 136 + wp + dj + 2];
        offs_l[tc * 128 + wp] = tanhf(acc + b_eff[tc]) * 5.0f;
    }
    __syncthreads();                             // B2: offs ready, rowsP dead

    // ---- Phase B: branch-free bilinear gather -> xsT ----
    {
        const short* xbase = x_bf + (size_t)b * IMG * 128;
#pragma unroll
        for (int it = 0; it < 8; ++it) {
            int id = t + it * 256;
            int px = id >> 4, c8 = id & 15;
            float ox = offs_l[px];
            float oy = offs_l[128 + px];
            float xg = ((float)px + ox) * (128.0f / 127.0f) - 0.5f;
            float yg = ((float)h  + oy) * (128.0f / 127.0f) - 0.5f;
            float x0f = floorf(xg), y0f = floorf(yg);
            float fx = xg - x0f, fy = yg - y0f;
            int x0 = (int)x0f, y0 = (int)y0f;
            float s[8];
#pragma unroll
            for (int r = 0; r < 8; ++r) s[r] = 0.f;
#pragma unroll
            for (int tap = 0; tap < 4; ++tap) {
                int xi = x0 + (tap & 1), yi = y0 + (tap >> 1);
                float wgt = ((tap & 1) ? fx : 1.f - fx) * ((tap >> 1) ? fy : 1.f - fy);
                wgt = (xi >= 0 && xi < 128 && yi >= 0 && yi < 128) ? wgt : 0.f;
                int xc = min(max(xi, 0), 127), yc = min(max(yi, 0), 127);
                short8 v = *reinterpret_cast<const short8*>(
                    xbase + ((size_t)(yc * 128 + xc)) * 128 + c8 * 8);
#pragma unroll
                for (int r = 0; r < 8; ++r) s[r] = fmaf(wgt, bf2f(v[r]), s[r]);
            }
            short8 o;
#pragma unroll
            for (int r = 0; r < 8; ++r) o[r] = f2bf(s[r]);
            *reinterpret_cast<short8*>(&xsT[px * 136 + c8 * 8]) = o;
        }
    }
    __syncthreads();                             // B3: xsT complete

    // ---- fused k & v GEMMs (shared A-frags from xsT) ----
    {
        floatx4 ak[4][4], av[4][4];
#pragma unroll
        for (int im = 0; im < 4; ++im)
#pragma unroll
            for (int in = 0; in < 4; ++in) {
                ak[im][in] = (floatx4){0.f, 0.f, 0.f, 0.f};
                av[im][in] = (floatx4){0.f, 0.f, 0.f, 0.f};
            }
#pragma unroll
        for (int kc = 0; kc < 128; kc += 32) {
            short8 af[4], bk_[4], bv_[4];
#pragma unroll
            for (int im = 0; im < 4; ++im)
                af[im] = *reinterpret_cast<const short8*>(
                    &xsT[(mh * 64 + im * 16 + l15) * 136 + kc + quad * 8]);
#pragma unroll
            for (int in = 0; in < 4; ++in) {
                bk_[in] = *reinterpret_cast<const short8*>(
                    wbf + 16384 + (nh * 64 + in * 16 + l15) * 128 + kc + quad * 8);
                bv_[in] = *reinterpret_cast<const short8*>(
                    wbf + 32768 + (nh * 64 + in * 16 + l15) * 128 + kc + quad * 8);
            }
#pragma unroll
            for (int im = 0; im < 4; ++im)
#pragma unroll
                for (int in = 0; in < 4; ++in) {
                    ak[im][in] = __builtin_amdgcn_mfma_f32_16x16x32_bf16(
                        af[im], bk_[in], ak[im][in], 0, 0, 0);
                    av[im][in] = __builtin_amdgcn_mfma_f32_16x16x32_bf16(
                        af[im], bv_[in], av[im][in], 0, 0, 0);
                }
        }
        __syncthreads();                         // B4: xsT reads done
        // stage k -> stg, biased v -> xsT (simultaneously)
#pragma unroll
        for (int in = 0; in < 4; ++in) {
            int o = nh * 64 + in * 16 + l15;
            float bbk = bk[o];
            float bbv = bv[o] + rel[o * 128 + h];
#pragma unroll
            for (int im = 0; im < 4; ++im) {
                int row0 = mh * 64 + im * 16 + quad * 4;
                short4v sk = {f2bf(ak[im][in][0] + bbk), f2bf(ak[im][in][1] + bbk),
                              f2bf(ak[im][in][2] + bbk), f2bf(ak[im][in][3] + bbk)};
                short4v sv = {f2bf(av[im][in][0] + bbv), f2bf(av[im][in][1] + bbv),
                              f2bf(av[im][in][2] + bbv), f2bf(av[im][in][3] + bbv)};
                *reinterpret_cast<short4v*>(&stg[o * 136 + row0]) = sk;
                *reinterpret_cast<short4v*>(&xsT[o * 136 + row0]) = sv;
            }
        }
    }
    __syncthreads();                             // B5
    // coalesced k write
    for (int id = t; id < 2048; id += 256) {
        int o = id >> 4, seg = id & 15;
        *reinterpret_cast<short8*>(
            k_bf + ((size_t)(b * 128 + o)) * IMG + h * 128 + seg * 8)
            = *reinterpret_cast<const short8*>(&stg[o * 136 + seg * 8]);
    }

    // ---- vw = v·Wo^T GEMM: D[o'][plane] = Σ_px Wo[o'][px]·v[plane][px] ----
    {
        const short* WoB = wbf + 49152;
        floatx4 aw[4][4];
#pragma unroll
        for (int im = 0; im < 4; ++im)
#pragma unroll
            for (int in = 0; in < 4; ++in)
                aw[im][in] = (floatx4){0.f, 0.f, 0.f, 0.f};
#pragma unroll
        for (int kc = 0; kc < 128; kc += 32) {
            short8 af[4], bf_[4];
#pragma unroll
            for (int im = 0; im < 4; ++im)
                af[im] = *reinterpret_cast<const short8*>(
                    WoB + (mh * 64 + im * 16 + l15) * 128 + kc + quad * 8);
#pragma unroll
            for (int in = 0; in < 4; ++in)
                bf_[in] = *reinterpret_cast<const short8*>(
                    &xsT[(nh * 64 + in * 16 + l15) * 136 + kc + quad * 8]);
#pragma unroll
            for (int im = 0; im < 4; ++im)
#pragma unroll
                for (int in = 0; in < 4; ++in)
                    aw[im][in] = __builtin_amdgcn_mfma_f32_16x16x32_bf16(
                        af[im], bf_[in], aw[im][in], 0, 0, 0);
        }
        __syncthreads();                         // B6: k-write stg reads done
        // stage vw: stg[plane][o'] (contig-4 along o' = quad*4+r)
#pragma unroll
        for (int in = 0; in < 4; ++in) {
            int plane = nh * 64 + in * 16 + l15;
#pragma unroll
            for (int im = 0; im < 4; ++im) {
                int row0 = mh * 64 + im * 16 + quad * 4;   // o' base
                short4v s = {f2bf(aw[im][in][0]), f2bf(aw[im][in][1]),
                             f2bf(aw[im][in][2]), f2bf(aw[im][in][3])};
                *reinterpret_cast<short4v*>(&stg[plane * 136 + row0]) = s;
            }
        }
    }
    __syncthreads();                             // B7
    // coalesced vw write into v_bf
    for (int id = t; id < 2048; id += 256) {
        int o = id >> 4, seg = id & 15;
        *reinterpret_cast<short8*>(
            v_bf + ((size_t)(b * 128 + o)) * IMG + h * 128 + seg * 8)
            = *reinterpret_cast<const short8*>(&stg[o * 136 + seg * 8]);
    }
}

// ---------------------------------------------------------------------------
// Kernel 4 (R15): MFMA attention, 2 phases. Phase 1: S=q·kT + softmax.
// Phase 2: Y = P·vw + bo (Wo pre-folded into vw by k_fused3). b64-packed
// vw->vT transpose; Y staged fp32 in LDS -> coalesced float4 stores.
// LDS: Pb 34816 + vT 34816 + redm 1024 + reds 1024 = 71680 B (2 blocks/CU).
// ---------------------------------------------------------------------------
__launch_bounds__(256, 2)
__global__ void k_attn3(const short* __restrict__ q_bf, const short* __restrict__ k_bf,
                        const short* __restrict__ v_bf,
                        const float* __restrict__ bo, float* __restrict__ outp) {
    __shared__ __align__(16) char smem[71680];
    short* Pb   = (short*)smem;                  // 34816 B: P bf16
    short* vT   = (short*)(smem + 34816);        // 34816 B: vw^T swizzled
    float* Ystg = (float*)smem;                  // 128x132 fp32 = 67584 B (epilogue)
    float* redm = (float*)(smem + 69632);        // 512 B x2
    float* reds = (float*)(smem + 70656);        // 512 B x2

    const int t = threadIdx.x;
    const int w = t >> 6, l = t & 63, l15 = l & 15, quad = l >> 4;
    const int mh = w >> 1, nh = w & 1;
    const size_t hb = (size_t)blockIdx.x * IMG;
    const short* qp = q_bf + hb;
    const short* kp = k_bf + hb;
    const short* vp = v_bf + hb;

    // ---- vw -> vT transpose (b64 writes, swizzled): 512 items, 2/thread ----
    for (int id = t; id < 512; id += 256) {
        int j4 = id >> 4, seg = id & 15;             // j-block of 4, d-block of 8
        const short* src = vp + (j4 * 4) * 128 + seg * 8;
        short8 v0 = *reinterpret_cast<const short8*>(src);
        short8 v1 = *reinterpret_cast<const short8*>(src + 128);
        short8 v2 = *reinterpret_cast<const short8*>(src + 256);
        short8 v3 = *reinterpret_cast<const short8*>(src + 384);
        int phys = (((j4 >> 1) ^ seg) & 15) * 8 + (j4 & 1) * 4;
#pragma unroll
        for (int r = 0; r < 8; ++r) {
            short4v wv = {v0[r], v1[r], v2[r], v3[r]};
            *reinterpret_cast<short4v*>(&vT[(seg * 8 + r) * 136 + phys]) = wv;
        }
    }

    floatx4 acc[4][4];
#pragma unroll
    for (int im = 0; im < 4; ++im)
#pragma unroll
        for (int in = 0; in < 4; ++in)
            acc[im][in] = (floatx4){0.f, 0.f, 0.f, 0.f};

    // ---- Phase 1: S = q·kT (direct-global frags) ----
#pragma unroll
    for (int kc = 0; kc < 128; kc += 32) {
        short8 af[4], bf_[4];
#pragma unroll
        for (int im = 0; im < 4; ++im)
            af[im] = *reinterpret_cast<const short8*>(
                qp + (mh * 64 + im * 16 + l15) * 128 + kc + quad * 8);
#pragma unroll
        for (int in = 0; in < 4; ++in)
            bf_[in] = *reinterpret_cast<const short8*>(
                kp + (nh * 64 + in * 16 + l15) * 128 + kc + quad * 8);
#pragma unroll
        for (int im = 0; im < 4; ++im)
#pragma unroll
            for (int in = 0; in < 4; ++in)
                acc[im][in] = __builtin_amdgcn_mfma_f32_16x16x32_bf16(
                    af[im], bf_[in], acc[im][in], 0, 0, 0);
    }

    const float scale = 0.08838834764831845f;
    float mloc[4][4];
#pragma unroll
    for (int im = 0; im < 4; ++im)
#pragma unroll
        for (int r = 0; r < 4; ++r) {
            float m = acc[im][0][r];
#pragma unroll
            for (int in = 1; in < 4; ++in) m = fmaxf(m, acc[im][in][r]);
            mloc[im][r] = m;
        }
#pragma unroll
    for (int mask = 1; mask < 16; mask <<= 1)
#pragma unroll
        for (int im = 0; im < 4; ++im)
#pragma unroll
            for (int r = 0; r < 4; ++r)
                mloc[im][r] = fmaxf(mloc[im][r], __shfl_xor(mloc[im][r], mask, 64));
    if (l15 == 0) {
#pragma unroll
        for (int im = 0; im < 4; ++im)
#pragma unroll
            for (int r = 0; r < 4; ++r)
                redm[nh * 128 + mh * 64 + im * 16 + quad * 4 + r] = mloc[im][r];
    }
    __syncthreads();
    float sloc[4][4];
#pragma unroll
    for (int im = 0; im < 4; ++im)
#pragma unroll
        for (int r = 0; r < 4; ++r) {
            int row = mh * 64 + im * 16 + quad * 4 + r;
            float m = fmaxf(redm[row], redm[128 + row]);
            float ss = 0.f;
#pragma unroll
            for (int in = 0; in < 4; ++in) {
                float e = __expf((acc[im][in][r] - m) * scale);
                acc[im][in][r] = e;
                ss += e;
            }
            sloc[im][r] = ss;
        }
#pragma unroll
    for (int mask = 1; mask < 16; mask <<= 1)
#pragma unroll
        for (int im = 0; im < 4; ++im)
#pragma unroll
            for (int r = 0; r < 4; ++r)
                sloc[im][r] += __shfl_xor(sloc[im][r], mask, 64);
    if (l15 == 0) {
#pragma unroll
        for (int im = 0; im < 4; ++im)
#pragma unroll
            for (int r = 0; r < 4; ++r)
                reds[nh * 128 + mh * 64 + im * 16 + quad * 4 + r] = sloc[im][r];
    }
    __syncthreads();
#pragma unroll
    for (int im = 0; im < 4; ++im)
#pragma unroll
        for (int r = 0; r < 4; ++r) {
            int row = mh * 64 + im * 16 + quad * 4 + r;
            float inv = 1.0f / (reds[row] + reds[128 + row]);
#pragma unroll
            for (int in = 0; in < 4; ++in) {
                int col = nh * 64 + in * 16 + l15;
                Pb[row * 136 + col] = f2bf(acc[im][in][r] * inv);
            }
        }
    __syncthreads();

    // ---- Phase 2: Y = P·vw (A=Pb, B=vT swizzled) + bo ----
    float bb[4];
#pragma unroll
    for (int in = 0; in < 4; ++in) bb[in] = bo[nh * 64 + in * 16 + l15];
#pragma unroll
    for (int im = 0; im < 4; ++im)
#pragma unroll
        for (int in = 0; in < 4; ++in)
            acc[im][in] = (floatx4){0.f, 0.f, 0.f, 0.f};
#pragma unroll
    for (int kc = 0; kc < 128; kc += 32) {
        short8 af[4], bf_[4];
#pragma unroll
        for (int im = 0; im < 4; ++im)
            af[im] = *reinterpret_cast<const short8*>(
                &Pb[(mh * 64 + im * 16 + l15) * 136 + kc + quad * 8]);
#pragma unroll
        for (int in = 0; in < 4; ++in) {
            int dRow = nh * 64 + in * 16 + l15;
            int cphys = (((kc >> 3) + quad) ^ (dRow >> 3)) & 15;
            bf_[in] = *reinterpret_cast<const short8*>(
                &vT[dRow * 136 + cphys * 8]);
        }
#pragma unroll
        for (int im = 0; im < 4; ++im)
#pragma unroll
            for (int in = 0; in < 4; ++in)
                acc[im][in] = __builtin_amdgcn_mfma_f32_16x16x32_bf16(
                    af[im], bf_[in], acc[im][in], 0, 0, 0);
    }
    __syncthreads();                             // Pb/vT reads done; Ystg aliases
#pragma unroll
    for (int im = 0; im < 4; ++im)
#pragma unroll
        for (int in = 0; in < 4; ++in) {
            int col = nh * 64 + in * 16 + l15;
#pragma unroll
            for (int r = 0; r < 4; ++r) {
                int row = mh * 64 + im * 16 + quad * 4 + r;
                Ystg[row * 132 + col] = acc[im][in][r] + bb[in];
            }
        }
    __syncthreads();
    // coalesced Y write: 4096 float4, 16/thread
    for (int id = t; id < 4096; id += 256) {
        int row = id >> 5, c4 = (id & 31) * 4;
        *reinterpret_cast<float4*>(outp + hb + (size_t)row * 128 + c4) =
            *reinterpret_cast<const float4*>(&Ystg[row * 132 + c4]);
    }
}

// ---------------------------------------------------------------------------
extern "C" void kernel_launch(void* const* d_in, const int* in_sizes, int n_in,
                              void* d_out, int out_size, void* d_ws, size_t ws_size,
                              hipStream_t stream) {
    const float* x   = (const float*)d_in[0];
    const float* Wq  = (const float*)d_in[2];
    const float* bq  = (const float*)d_in[3];
    const float* Wk  = (const float*)d_in[4];
    const float* bk  = (const float*)d_in[5];
    const float* Wv  = (const float*)d_in[6];
    const float* bv  = (const float*)d_in[7];
    const float* Wo  = (const float*)d_in[8];
    const float* bo  = (const float*)d_in[9];
    const float* Wc1 = (const float*)d_in[10];
    const float* bc1 = (const float*)d_in[11];
    const float* Wc2 = (const float*)d_in[12];
    const float* rel = (const float*)d_in[13];

    char* wsb = (char*)d_ws;
    short* q_bf  = (short*)(wsb);                       // 16 MB
    short* k_bf  = (short*)(wsb + 1ull * 16777216);
    short* v_bf  = (short*)(wsb + 2ull * 16777216);
    short* x_bf  = (short*)(wsb + 3ull * 16777216);
    float* P     = (float*)(wsb + 4ull * 16777216);     // 13.1 MB
    float* W2    = (float*)(wsb + 4ull * 16777216 + 13107200);
    float* cst   = W2 + 6400;
    float* b_eff = cst + 64;
    short* wbf   = (short*)(b_eff + 16);                // 4 x 16384 bf16
    short* w2h   = wbf + 65536;                         // 64x128 bf16 (hi)
    short* w2l   = w2h + 8192;                          // 64x128 bf16 (lo)
    float* outp  = (float*)d_out;

    hipLaunchKernelGGL(k_wprep,  dim3(82),   dim3(256), 0, stream, Wc1, Wc2, bc1, Wq, bq,
                       Wk, Wv, Wo, W2, cst, b_eff, wbf, w2h, w2l);
    hipLaunchKernelGGL(k_off,    dim3(512),  dim3(256), 0, stream, x, w2h, w2l, cst,
                       bq, wbf, P, x_bf, q_bf);
    hipLaunchKernelGGL(k_fused3, dim3(512),  dim3(256), 0, stream, P, b_eff, x_bf, wbf,
                       bk, bv, rel, k_bf, v_bf);
    hipLaunchKernelGGL(k_attn3,  dim3(512),  dim3(256), 0, stream, q_bf, k_bf, v_bf,
                       bo, outp);
}